// Round 1
// 212.504 us; speedup vs baseline: 1.0813x; 1.0813x over previous
//
#include <hip/hip_runtime.h>

typedef unsigned short u16;
typedef unsigned int u32;
typedef __attribute__((ext_vector_type(8))) short bf16x8;
typedef __attribute__((ext_vector_type(4))) short bf16x4;
typedef __attribute__((ext_vector_type(4))) float f32x4;

#define CSC 0.1803368801111244f  // 0.125 * log2(e), folded into K at projection

__device__ __forceinline__ u16 f2b(float f) {
  union { float f; u32 u; } c; c.f = f;
  return (u16)((c.u + 0x8000u) >> 16);
}

// pack 4 f32 -> 4 bf16 as uint2 (elem0 = low u16 of .x)
__device__ __forceinline__ uint2 pk4(f32x4 p) {
  union { float f; u32 u; } c0, c1, c2, c3;
  c0.f = p[0]; c1.f = p[1]; c2.f = p[2]; c3.f = p[3];
  u32 a = c0.u + 0x8000u, b = c1.u + 0x8000u;
  u32 c = c2.u + 0x8000u, d = c3.u + 0x8000u;
  uint2 r;
  r.x = __builtin_amdgcn_perm(b, a, 0x07060302u);
  r.y = __builtin_amdgcn_perm(d, c, 0x07060302u);
  return r;
}

// pack 4 f32 -> bf16x4 via v_cvt_pk_bf16_f32 (2 instrs instead of 6)
__device__ __forceinline__ bf16x4 pk4cvt(f32x4 p) {
  union { uint2 u; bf16x4 v; } c;
  asm("v_cvt_pk_bf16_f32 %0, %1, %2" : "=v"(c.u.x) : "v"(p[0]), "v"(p[1]));
  asm("v_cvt_pk_bf16_f32 %0, %1, %2" : "=v"(c.u.y) : "v"(p[2]), "v"(p[3]));
  return c.v;
}

__device__ __forceinline__ void async16(const void* g, void* s) {
  __builtin_amdgcn_global_load_lds(
      (const __attribute__((address_space(1))) u32*)g,
      (__attribute__((address_space(3))) u32*)s, 16, 0, 0);
}

// ---------------- fused prep ----------------
// [0,4096) cvt x | [4096,10240) cvt ctx | [10240,10560) LDS-tiled W transpose |
// [10560,10562) mask -> mvalid floats + per-batch masked count
__global__ void prep(const float* __restrict__ x, const float* __restrict__ ctx,
                     const int* __restrict__ mask,
                     const float* __restrict__ Wq, const float* __restrict__ Wk,
                     const float* __restrict__ Wv, const float* __restrict__ Wo,
                     u16* __restrict__ Xb, u16* __restrict__ Cb,
                     float* __restrict__ mvalid, float* __restrict__ cnt,
                     u16* __restrict__ Wtq, u16* __restrict__ Wtkv, u16* __restrict__ Wto) {
  __shared__ u16 Tl[64 * 65];
  __shared__ int cred[4];
  const int bid = blockIdx.x, tid = threadIdx.x;
  if (bid < 10240) {
    const float* src; u16* dst; int i;
    if (bid < 4096) { i = (bid * 256 + tid) * 4; src = x; dst = Xb; }
    else { i = ((bid - 4096) * 256 + tid) * 4; src = ctx; dst = Cb; }
    float4 f = *(const float4*)&src[i];
    ushort4 o;
    o.x = f2b(f.x); o.y = f2b(f.y); o.z = f2b(f.z); o.w = f2b(f.w);
    *(ushort4*)&dst[i] = o;
  } else if (bid < 10560) {
    int t = bid - 10240;
    const float* W; u16* Wt; int Kd, tt;
    if (t < 64)       { W = Wq; Wt = Wtq;  Kd = 512; tt = t; }
    else if (t < 160) { W = Wk; Wt = Wtkv; Kd = 768; tt = t - 64; }
    else if (t < 256) { W = Wv; Wt = Wtkv + (size_t)512 * 768; Kd = 768; tt = t - 160; }
    else              { W = Wo; Wt = Wto;  Kd = 512; tt = t - 256; }
    const int k0 = (tt >> 3) * 64, n0 = (tt & 7) * 64;
    {
      const int r = tid >> 2, cg = (tid & 3) * 16;
#pragma unroll
      for (int i = 0; i < 4; i++) {
        float4 f = *(const float4*)&W[(size_t)(k0 + r) * 512 + n0 + cg + i * 4];
        Tl[r * 65 + cg + i * 4 + 0] = f2b(f.x);
        Tl[r * 65 + cg + i * 4 + 1] = f2b(f.y);
        Tl[r * 65 + cg + i * 4 + 2] = f2b(f.z);
        Tl[r * 65 + cg + i * 4 + 3] = f2b(f.w);
      }
    }
    __syncthreads();
    {
      const int n = tid >> 2, kg = (tid & 3) * 16;
      u16 buf[16];
#pragma unroll
      for (int i = 0; i < 16; i++) buf[i] = Tl[(kg + i) * 65 + n];
      u16* dst = &Wt[(size_t)(n0 + n) * Kd + k0 + kg];
      *(uint4*)dst = *(const uint4*)&buf[0];
      *(uint4*)(dst + 8) = *(const uint4*)&buf[8];
    }
  } else {
    const int b = bid - 10560;
    const int base = b * 4096;
    const int w = tid >> 6, lane = tid & 63;
    int zc = 0;
#pragma unroll
    for (int j = 0; j < 16; j++) {
      int idx = tid + j * 256;
      int mv = mask[base + idx];
      mvalid[base + idx] = mv ? 1.f : 0.f;
      zc += (mv == 0);
    }
#pragma unroll
    for (int d = 1; d < 64; d <<= 1) zc += __shfl_xor(zc, d);
    if (lane == 0) cred[w] = zc;
    __syncthreads();
    if (tid == 0) cnt[b] = (float)(cred[0] + cred[1] + cred[2] + cred[3]);
  }
}

// ---------------- fused QKV projection GEMM, 64x128 tiles ----------------
// grid (128, 12): y<4 -> Q-proj (A=Xb, K=512) cols y*128; y>=4 -> KV (A=Cb, K=768),
// cols (y-4)*128: <512 -> K' = K*CSC*mask row-major; >=512 -> V' = V*mask as V^T.
__global__ __launch_bounds__(256, 6)
void gemm_qkv(const u16* __restrict__ Xb, const u16* __restrict__ Cb,
              const u16* __restrict__ Wtq, const u16* __restrict__ Wtkv,
              const float* __restrict__ mvalid,
              u16* __restrict__ Qb, u16* __restrict__ Kb, u16* __restrict__ Vt) {
  __shared__ u16 As[64 * 64];
  __shared__ u16 Bs[128 * 64];
  const int tid = threadIdx.x;
  const int w = tid >> 6, lane = tid & 63, quad = lane >> 4, l16 = lane & 15;
  const int wr = w >> 1, wc = w & 1;
  const int y = blockIdx.y;
  const bool isQ = (y < 4);
  const u16* A  = isQ ? Xb : Cb;
  const u16* Bt = isQ ? Wtq : Wtkv;
  const int K   = isQ ? 512 : 768;
  const int n0  = isQ ? y * 128 : (y - 4) * 128;
  const size_t m0 = (size_t)blockIdx.x * 64;
  const u16* Ab = A + m0 * K;
  const u16* Bb = Bt + (size_t)n0 * K;

  const int cswz = (((lane & 7) ^ ((lane >> 3) & 7)) << 3);
  const int sw0 = ((quad ^ (l16 & 7)) << 3);
  const int sw1 = sw0 ^ 32;
  const int r8 = lane >> 3;

  f32x4 acc[2][4];
#pragma unroll
  for (int i = 0; i < 2; i++)
#pragma unroll
    for (int j = 0; j < 4; j++) acc[i][j] = (f32x4){0.f, 0.f, 0.f, 0.f};

  for (int k0 = 0; k0 < K; k0 += 64) {
    async16(Ab + (size_t)(w * 16 + r8) * K + k0 + cswz, &As[(w * 16) * 64]);
    async16(Ab + (size_t)(w * 16 + 8 + r8) * K + k0 + cswz, &As[(w * 16 + 8) * 64]);
#pragma unroll
    for (int t = 0; t < 4; t++)
      async16(Bb + (size_t)(w * 32 + t * 8 + r8) * K + k0 + cswz, &Bs[(w * 32 + t * 8) * 64]);
    __syncthreads();
#pragma unroll
    for (int ks = 0; ks < 2; ks++) {
      const int so = ks ? sw1 : sw0;
      bf16x8 af[2], bfr[4];
#pragma unroll
      for (int i = 0; i < 2; i++)
        af[i] = *(const bf16x8*)&As[(wr * 32 + i * 16 + l16) * 64 + so];
#pragma unroll
      for (int j = 0; j < 4; j++)
        bfr[j] = *(const bf16x8*)&Bs[(wc * 64 + j * 16 + l16) * 64 + so];
#pragma unroll
      for (int i = 0; i < 2; i++)
#pragma unroll
        for (int j = 0; j < 4; j++)
          acc[i][j] = __builtin_amdgcn_mfma_f32_16x16x32_bf16(af[i], bfr[j], acc[i][j], 0, 0, 0);
    }
    __syncthreads();
  }

  if (isQ) {
#pragma unroll
    for (int i = 0; i < 2; i++)
#pragma unroll
      for (int j = 0; j < 4; j++)
#pragma unroll
        for (int r = 0; r < 4; r++) {
          size_t row = m0 + wr * 32 + i * 16 + quad * 4 + r;
          Qb[row * 512 + n0 + wc * 64 + j * 16 + l16] = f2b(acc[i][j][r]);
        }
  } else if (n0 < 512) {
    // K' = K * CSC * mask (masked context rows -> exact 0)
#pragma unroll
    for (int i = 0; i < 2; i++) {
      size_t row0 = m0 + wr * 32 + i * 16 + quad * 4;
      f32x4 vm = *(const f32x4*)&mvalid[row0];
#pragma unroll
      for (int j = 0; j < 4; j++)
#pragma unroll
        for (int r = 0; r < 4; r++)
          Kb[(row0 + r) * 512 + n0 + wc * 64 + j * 16 + l16] = f2b(acc[i][j][r] * (vm[r] * CSC));
    }
  } else {
    // V' = V * mask, stored transposed: Vt[d][8192]
#pragma unroll
    for (int i = 0; i < 2; i++) {
      size_t row0 = m0 + wr * 32 + i * 16 + quad * 4;
      f32x4 vm = *(const f32x4*)&mvalid[row0];
#pragma unroll
      for (int j = 0; j < 4; j++) {
        int d = n0 - 512 + wc * 64 + j * 16 + l16;
        f32x4 v;
#pragma unroll
        for (int r = 0; r < 4; r++) v[r] = acc[i][j][r] * vm[r];
        *(uint2*)&Vt[(size_t)d * 8192 + row0] = pk4(v);
      }
    }
  }
}

// ---------------- O projection: 64x64 tiles, grid (128, 8) = 4 blocks/CU ----------------
__global__ __launch_bounds__(256, 4)
void gemm_o(const u16* __restrict__ A, const u16* __restrict__ Bt,
            const float* __restrict__ bias, float* __restrict__ Cf) {
  __shared__ u16 As[64 * 64];
  __shared__ u16 Bs[64 * 64];
  const int tid = threadIdx.x;
  const int w = tid >> 6, lane = tid & 63, quad = lane >> 4, l16 = lane & 15;
  const size_t m0 = (size_t)blockIdx.x * 64;
  const int n0 = blockIdx.y * 64;
  const u16* Ab = A + m0 * 512;
  const u16* Bb = Bt + (size_t)n0 * 512;

  const int cswz = (((lane & 7) ^ ((lane >> 3) & 7)) << 3);
  const int sw0 = ((quad ^ (l16 & 7)) << 3);
  const int sw1 = sw0 ^ 32;
  const int r8 = lane >> 3;

  f32x4 acc[4];
#pragma unroll
  for (int j = 0; j < 4; j++) acc[j] = (f32x4){0.f, 0.f, 0.f, 0.f};

  for (int k0 = 0; k0 < 512; k0 += 64) {
    async16(Ab + (size_t)(w * 16 + r8) * 512 + k0 + cswz, &As[(w * 16) * 64]);
    async16(Ab + (size_t)(w * 16 + 8 + r8) * 512 + k0 + cswz, &As[(w * 16 + 8) * 64]);
    async16(Bb + (size_t)(w * 16 + r8) * 512 + k0 + cswz, &Bs[(w * 16) * 64]);
    async16(Bb + (size_t)(w * 16 + 8 + r8) * 512 + k0 + cswz, &Bs[(w * 16 + 8) * 64]);
    __syncthreads();
#pragma unroll
    for (int ks = 0; ks < 2; ks++) {
      const int so = ks ? sw1 : sw0;
      bf16x8 af = *(const bf16x8*)&As[(w * 16 + l16) * 64 + so];
#pragma unroll
      for (int j = 0; j < 4; j++) {
        bf16x8 bfr = *(const bf16x8*)&Bs[(j * 16 + l16) * 64 + so];
        acc[j] = __builtin_amdgcn_mfma_f32_16x16x32_bf16(af, bfr, acc[j], 0, 0, 0);
      }
    }
    __syncthreads();
  }

#pragma unroll
  for (int j = 0; j < 4; j++)
#pragma unroll
    for (int r = 0; r < 4; r++) {
      size_t row = m0 + w * 16 + quad * 4 + r;
      int col = n0 + j * 16 + l16;
      Cf[row * 512 + col] = acc[j][r] + bias[col];
    }
}

// ---------------- flash attention: 64-row Q blocks, 4 blocks/CU ----------------
// grid 1024 (l>>4 = qb, l&15 = hb; h = hb>>1, b = hb&1), block 256 (4 waves).
// Waves split 2x2 over (q, m): wave (wq, wm) owns the 32q x 32m quadrant of the
// 64x64 score tile. Each K/V LDS fragment now feeds TWO mfmas (register-tile
// reuse in q) -> ds_read traffic per wave-mt halves (16KB -> 8KB) at unchanged
// grid/occupancy. Partial Oacc/lsum over the m-split are combined through LDS
// (reusing the K/V buffers) once per block at the epilogue.
// K pre-scaled by CSC and masked-to-zero; V masked-to-zero. p = exp2(s) directly;
// masked positions give p=1 exactly, corrected by subtracting cnt[b] from l.
// S^T C-layout feeds PV 16x16x16 B-operand straight from registers.
__global__ __launch_bounds__(256, 4)
void attn_kernel(const u16* __restrict__ Q, const u16* __restrict__ Kg,
                 const u16* __restrict__ Vt, const float* __restrict__ cnt,
                 u16* __restrict__ AO) {
  __shared__ u16 Ks[2][64 * 64];
  __shared__ u16 Vs[2][64 * 64];

  const int tid = threadIdx.x;
  const int w = tid >> 6, lane = tid & 63, quad = lane >> 4, l16 = lane & 15;
  const int wq = w >> 1, wm = w & 1;
  const int l = blockIdx.x;
  const int qb = l >> 4, hb = l & 15, h = hb >> 1, b = hb & 1;
  const size_t qrow0 = (size_t)b * 4096 + (size_t)qb * 64;
  const size_t crow0 = (size_t)b * 4096;
  const int hcol = h * 64;
  const float cb = cnt[b];

  const int cswz = (((lane & 7) ^ ((lane >> 3) & 7)) << 3);
  const int sw0 = ((quad ^ (l16 & 7)) << 3);
  const int sw1 = sw0 ^ 32;
  const int r8 = lane >> 3;

  // Q B-fragments straight from global (rows contiguous b128): qf[qt][ks]
  bf16x8 qf[2][2];
#pragma unroll
  for (int qt = 0; qt < 2; qt++)
#pragma unroll
    for (int ks = 0; ks < 2; ks++)
      qf[qt][ks] = *(const bf16x8*)&Q[(qrow0 + wq * 32 + qt * 16 + l16) * 512 +
                                      hcol + ks * 32 + quad * 8];

  // stage K/V tile 0 (all 4 waves cooperate, 16 rows each)
  async16(Kg + (crow0 + w * 16 + r8) * 512 + hcol + cswz, &Ks[0][(w * 16) * 64]);
  async16(Kg + (crow0 + w * 16 + 8 + r8) * 512 + hcol + cswz, &Ks[0][(w * 16 + 8) * 64]);
  async16(Vt + (size_t)(hcol + w * 16 + r8) * 8192 + crow0 + cswz, &Vs[0][(w * 16) * 64]);
  async16(Vt + (size_t)(hcol + w * 16 + 8 + r8) * 8192 + crow0 + cswz, &Vs[0][(w * 16 + 8) * 64]);
  __syncthreads();

  f32x4 Oacc[2][4];  // [qt][dt]: D[d][q] partial over this wave's m-range
#pragma unroll
  for (int qt = 0; qt < 2; qt++)
#pragma unroll
    for (int dt = 0; dt < 4; dt++) Oacc[qt][dt] = (f32x4){0.f, 0.f, 0.f, 0.f};
  float lsum[2] = {0.f, 0.f};

  for (int mt = 0; mt < 64; mt++) {
    const int cur = mt & 1;
    const size_t m0 = (size_t)mt * 64;

    if (mt < 63) {
      const size_t mn = m0 + 64;
      async16(Kg + (crow0 + mn + w * 16 + r8) * 512 + hcol + cswz, &Ks[cur ^ 1][(w * 16) * 64]);
      async16(Kg + (crow0 + mn + w * 16 + 8 + r8) * 512 + hcol + cswz, &Ks[cur ^ 1][(w * 16 + 8) * 64]);
      async16(Vt + (size_t)(hcol + w * 16 + r8) * 8192 + crow0 + mn + cswz, &Vs[cur ^ 1][(w * 16) * 64]);
      async16(Vt + (size_t)(hcol + w * 16 + 8 + r8) * 8192 + crow0 + mn + cswz, &Vs[cur ^ 1][(w * 16 + 8) * 64]);
    }

    // S^T = mfma_16x16x32(A=K'[m][d], B=Q[q][d]) -> D[m][q]; each kb reused for 2 qt
    f32x4 sacc[2][2];  // [qt][mtt]
#pragma unroll
    for (int qt = 0; qt < 2; qt++)
#pragma unroll
      for (int mtt = 0; mtt < 2; mtt++) sacc[qt][mtt] = (f32x4){0.f, 0.f, 0.f, 0.f};
#pragma unroll
    for (int ks = 0; ks < 2; ks++) {
      const int so = ks ? sw1 : sw0;
#pragma unroll
      for (int mtt = 0; mtt < 2; mtt++) {
        bf16x8 kb = *(const bf16x8*)&Ks[cur][(wm * 32 + mtt * 16 + l16) * 64 + so];
#pragma unroll
        for (int qt = 0; qt < 2; qt++)
          sacc[qt][mtt] = __builtin_amdgcn_mfma_f32_16x16x32_bf16(kb, qf[qt][ks], sacc[qt][mtt], 0, 0, 0);
      }
    }

    // p = exp2(s); masked rows give exactly 1 (subtracted later via cnt)
    bf16x4 pf[2][2];  // [qt][mtt]
#pragma unroll
    for (int qt = 0; qt < 2; qt++)
#pragma unroll
      for (int mtt = 0; mtt < 2; mtt++) {
        f32x4 p;
#pragma unroll
        for (int r = 0; r < 4; r++) {
          p[r] = __builtin_amdgcn_exp2f(sacc[qt][mtt][r]);
          lsum[qt] += p[r];
        }
        pf[qt][mtt] = pk4cvt(p);
      }

    // O^T += mfma_16x16x16(A=V'^T[d][m-chunk], B=P); each va reused for 2 qt
#pragma unroll
    for (int mtt = 0; mtt < 2; mtt++) {
#pragma unroll
      for (int dt = 0; dt < 4; dt++) {
        bf16x4 va = *(const bf16x4*)&Vs[cur][(dt * 16 + l16) * 64 +
                      (((wm * 4 + mtt * 2 + (quad >> 1)) ^ (l16 & 7)) << 3) + ((quad & 1) << 2)];
#pragma unroll
        for (int qt = 0; qt < 2; qt++)
          Oacc[qt][dt] = __builtin_amdgcn_mfma_f32_16x16x16bf16_1k(va, pf[qt][mtt], Oacc[qt][dt], 0, 0, 0);
      }
    }
    __syncthreads();
  }

  // reduce l across quads (same q = qt*16 + l16)
#pragma unroll
  for (int qt = 0; qt < 2; qt++) {
    lsum[qt] += __shfl_xor(lsum[qt], 16);
    lsum[qt] += __shfl_xor(lsum[qt], 32);
  }

  // cross-wave (wm) reduction through LDS: K/V buffers are free after final barrier.
  float* red  = (float*)&Ks[0][0];  // 16 KB: [wq][qt*4+dt][lane] f32x4
  float* lred = (float*)&Vs[0][0];  // 1 KB: [wq][qt][lane]
  if (wm == 1) {
#pragma unroll
    for (int qt = 0; qt < 2; qt++) {
#pragma unroll
      for (int dt = 0; dt < 4; dt++)
        *(f32x4*)&red[wq * 2048 + (qt * 4 + dt) * 256 + lane * 4] = Oacc[qt][dt];
      lred[wq * 128 + qt * 64 + lane] = lsum[qt];
    }
  }
  __syncthreads();
  if (wm == 0) {
#pragma unroll
    for (int qt = 0; qt < 2; qt++) {
      const float inv = 1.0f / (lsum[qt] + lred[wq * 128 + qt * 64 + lane] - cb);
#pragma unroll
      for (int dt = 0; dt < 4; dt++) {
        f32x4 part = *(const f32x4*)&red[wq * 2048 + (qt * 4 + dt) * 256 + lane * 4];
        f32x4 o;
#pragma unroll
        for (int r = 0; r < 4; r++) o[r] = (Oacc[qt][dt][r] + part[r]) * inv;
        *(uint2*)&AO[(qrow0 + wq * 32 + qt * 16 + l16) * 512 + hcol + dt * 16 + quad * 4] = pk4(o);
      }
    }
  }
}

// ---------------- host ----------------

extern "C" void kernel_launch(void* const* d_in, const int* in_sizes, int n_in,
                              void* d_out, int out_size, void* d_ws, size_t ws_size,
                              hipStream_t stream) {
  const float* x   = (const float*)d_in[0];
  const float* ctx = (const float*)d_in[1];
  const int*  mask = (const int*)d_in[2];
  const float* Wq  = (const float*)d_in[3];
  const float* Wk  = (const float*)d_in[4];
  const float* Wv  = (const float*)d_in[5];
  const float* Wo  = (const float*)d_in[6];
  const float* bo  = (const float*)d_in[7];
  float* out = (float*)d_out;

  char* p = (char*)d_ws;
  u16* Xb   = (u16*)p; p += (size_t)8192 * 512 * 2;
  u16* Cb   = (u16*)p; p += (size_t)8192 * 768 * 2;
  u16* Wtq  = (u16*)p; p += (size_t)512 * 512 * 2;
  u16* Wtkv = (u16*)p; p += (size_t)1024 * 768 * 2;
  u16* Wto  = (u16*)p; p += (size_t)512 * 512 * 2;
  u16* Qb   = (u16*)p; p += (size_t)8192 * 512 * 2;
  u16* Kb   = (u16*)p; p += (size_t)8192 * 512 * 2;
  u16* Vtg  = (u16*)p; p += (size_t)512 * 8192 * 2;
  u16* AOb  = (u16*)p; p += (size_t)8192 * 512 * 2;
  float* mvalid = (float*)p; p += (size_t)8192 * 4;
  float* cnt    = (float*)p; p += 2 * 4;

  prep<<<10562, 256, 0, stream>>>(x, ctx, mask, Wq, Wk, Wv, Wo,
                                  Xb, Cb, mvalid, cnt, Wtq, Wtkv, Wto);
  gemm_qkv<<<dim3(128, 12), 256, 0, stream>>>(Xb, Cb, Wtq, Wtkv, mvalid, Qb, Kb, Vtg);
  attn_kernel<<<1024, 256, 0, stream>>>(Qb, Kb, Vtg, cnt, AOb);
  gemm_o<<<dim3(128, 8), 256, 0, stream>>>(AOb, Wto, bo, out);
}